// Round 3
// baseline (11896.321 us; speedup 1.0000x reference)
//
#include <hip/hip_runtime.h>

#define T_STEPS 4096
#define HD 2048
#define G4 8192
#define NWG 256
#define NTH 1024
#define SENT 0x7FC0DEADu
#define SMEM_BYTES (131072 + 8192 + 128)

typedef __attribute__((ext_vector_type(8))) short bf16x8;
typedef __attribute__((ext_vector_type(4))) float f32x4;
typedef __attribute__((ext_vector_type(2))) float f32x2;
typedef __attribute__((ext_vector_type(8))) unsigned short u16x8;

static __device__ __forceinline__ unsigned short f2bf(float f){
  union { float f; unsigned int u; } v; v.f = f;
  unsigned int r = (v.u + 0x7fffu + ((v.u >> 16) & 1u)) >> 16;
  return (unsigned short)r;
}
static __device__ __forceinline__ float bf2f(unsigned short s){
  union { unsigned int u; float f; } v; v.u = ((unsigned int)s) << 16;
  return v.f;
}
static __device__ __forceinline__ float blo(unsigned int u){
  return __uint_as_float(u << 16);
}
static __device__ __forceinline__ float bhi(unsigned int u){
  return __uint_as_float(u & 0xffff0000u);
}

// uncached (coherence-point) 8B load — bypasses L1/L2 so no fences needed
static __device__ __forceinline__ f32x2 ld2_uc(const float* p){
  f32x2 r;
  asm volatile("global_load_dwordx2 %0, %1, off sc0 sc1\n\ts_waitcnt vmcnt(0)"
               : "=v"(r) : "v"(p) : "memory");
  return r;
}
// write-through 4B store
static __device__ __forceinline__ void st_uc(float* p, float v){
  asm volatile("global_store_dword %0, %1, off sc0 sc1" :: "v"(p), "v"(v) : "memory");
}

// ---------------- init: bias fuse + h0 zeros + sentinel rows ----------------
__global__ void init_kernel(const float* __restrict__ b_ih, const float* __restrict__ b_hh,
                            float* __restrict__ bias, float* __restrict__ Hbuf){
  int i = blockIdx.x*blockDim.x + threadIdx.x;
  int stride = gridDim.x*blockDim.x;
  const int NTOT = G4 + (T_STEPS+1)*HD;
  union { unsigned int u; float f; } sent; sent.u = SENT;
  for (int idx = i; idx < NTOT; idx += stride){
    if (idx < G4) bias[idx] = b_ih[idx] + b_hh[idx];
    else {
      int j = idx - G4;
      Hbuf[j] = (j < HD) ? 0.f : sent.f;
    }
  }
}

// ---------------- phase 1: XP = x @ W_ih^T + (b_ih+b_hh), bf16 out ----------------
__global__ __launch_bounds__(256) void gemm_xp(const float* __restrict__ X,
                                               const float* __restrict__ W,
                                               const float* __restrict__ bias,
                                               unsigned short* __restrict__ XP){
  __shared__ __align__(16) unsigned short As[128][40];
  __shared__ __align__(16) unsigned short Bs[128][40];
  const int tid = threadIdx.x;
  const int bx = blockIdx.x & 63;
  const int by = blockIdx.x >> 6;
  const int row0 = by*128, col0 = bx*128;
  const int l = tid & 63, w = tid >> 6;
  const int wrow = (w>>1)*64, wcol = (w&1)*64;
  const int lr = l & 15, lk = l >> 4;

  f32x4 acc[4][4];
  #pragma unroll
  for (int mi=0; mi<4; mi++)
    #pragma unroll
    for (int ni=0; ni<4; ni++)
      acc[mi][ni] = (f32x4){0.f,0.f,0.f,0.f};

  const int sr = tid >> 1;
  const int sh = (tid & 1) * 16;
  const float* xb = X + (size_t)(row0+sr)*2048 + sh;
  const float* wb = W + (size_t)(col0+sr)*2048 + sh;

  for (int k0 = 0; k0 < 2048; k0 += 32){
    __syncthreads();
    u16x8 va[2], vb[2];
    #pragma unroll
    for (int q=0; q<2; q++){
      float4 u = *(const float4*)(xb + k0 + q*8);
      float4 v = *(const float4*)(xb + k0 + q*8 + 4);
      u16x8 t;
      t[0]=f2bf(u.x); t[1]=f2bf(u.y); t[2]=f2bf(u.z); t[3]=f2bf(u.w);
      t[4]=f2bf(v.x); t[5]=f2bf(v.y); t[6]=f2bf(v.z); t[7]=f2bf(v.w);
      va[q]=t;
      float4 p = *(const float4*)(wb + k0 + q*8);
      float4 r = *(const float4*)(wb + k0 + q*8 + 4);
      u16x8 s;
      s[0]=f2bf(p.x); s[1]=f2bf(p.y); s[2]=f2bf(p.z); s[3]=f2bf(p.w);
      s[4]=f2bf(r.x); s[5]=f2bf(r.y); s[6]=f2bf(r.z); s[7]=f2bf(r.w);
      vb[q]=s;
    }
    *(u16x8*)&As[sr][sh]   = va[0];
    *(u16x8*)&As[sr][sh+8] = va[1];
    *(u16x8*)&Bs[sr][sh]   = vb[0];
    *(u16x8*)&Bs[sr][sh+8] = vb[1];
    __syncthreads();

    bf16x8 af[4], bfr[4];
    #pragma unroll
    for (int mi=0; mi<4; mi++) af[mi]  = *(const bf16x8*)&As[wrow+mi*16+lr][lk*8];
    #pragma unroll
    for (int ni=0; ni<4; ni++) bfr[ni] = *(const bf16x8*)&Bs[wcol+ni*16+lr][lk*8];
    #pragma unroll
    for (int mi=0; mi<4; mi++)
      #pragma unroll
      for (int ni=0; ni<4; ni++)
        acc[mi][ni] = __builtin_amdgcn_mfma_f32_16x16x32_bf16(af[mi], bfr[ni], acc[mi][ni], 0,0,0);
  }

  #pragma unroll
  for (int ni=0; ni<4; ni++){
    const int jc = col0 + wcol + ni*16 + lr;
    const float bv = bias[jc];
    #pragma unroll
    for (int mi=0; mi<4; mi++){
      const int tr0 = row0 + wrow + mi*16 + lk*4;
      #pragma unroll
      for (int r=0; r<4; r++)
        XP[(size_t)(tr0+r)*G4 + jc] = f2bf(acc[mi][ni][r] + bv);
    }
  }
}

// ---------------- phase 2: persistent LSTM recurrence ----------------
// 256 WGs x 1024 thr (16 waves). WG g owns h-dims [8g,8g+8) = 32 gate rows
// (rr = gate*8 + dd). Wave w owns rows 2w, 2w+1; lane l covers k = c*256+l*4
// (c=0..7). Weights live in LDS as packed bf16 (128 KB, deterministic —
// registers proved unreliable in R1/R2: compiler spilled to scratch).
// LDS weight layout: block b = ri*4+cp at byte (b*1024+tid)*16, holding
// 8 bf16: k-chunks 2cp and 2cp+1. Conflict-free (lanes read consecutive 16B).
// Sync: sentinel-poll on uncached loads, write-through publish, no fences.
__global__ __launch_bounds__(NTH, 4) void recur(const unsigned short* __restrict__ XP,
                                                const float* __restrict__ Whh,
                                                float* __restrict__ Hbuf){
  extern __shared__ char smem[];
  float* h_lds = (float*)(smem + 131072);
  float* gsum  = (float*)(smem + 131072 + 8192);
  const int g = blockIdx.x;
  const int tid = threadIdx.x;
  const int l = tid & 63, w = tid >> 6;

  // stage weights into LDS as packed bf16
  #pragma unroll
  for (int ri=0; ri<2; ri++){
    const int rr = 2*w + ri;
    const size_t jrow = (size_t)(rr>>3)*HD + (size_t)g*8 + (rr&7);
    const float* wp = Whh + jrow*HD + l*4;
    #pragma unroll
    for (int cp=0; cp<4; cp++){
      float4 fa = *(const float4*)(wp + (2*cp)*256);
      float4 fb = *(const float4*)(wp + (2*cp+1)*256);
      uint4 pk;
      pk.x = ((unsigned)f2bf(fa.y)<<16) | f2bf(fa.x);
      pk.y = ((unsigned)f2bf(fa.w)<<16) | f2bf(fa.z);
      pk.z = ((unsigned)f2bf(fb.y)<<16) | f2bf(fb.x);
      pk.w = ((unsigned)f2bf(fb.w)<<16) | f2bf(fb.z);
      *(uint4*)(smem + (size_t)((ri*4+cp)*1024 + tid)*16) = pk;
    }
  }

  float c_reg = 0.f;      // cell state (lanes tid<8)
  float xpv[4] = {0,0,0,0};

  for (int t=0; t<T_STEPS; ++t){
    // XP slice for the cell lanes — private regs (no LDS race)
    if (tid < 8){
      #pragma unroll
      for (int q=0; q<4; q++)
        xpv[q] = bf2f(XP[(size_t)t*G4 + (size_t)q*HD + g*8 + tid]);
    }
    // spin-wait on own 8B of h[t-1] (row t; row 0 = zeros)
    const float* hp = Hbuf + (size_t)t*HD + tid*2;
    f32x2 hv;
    do {
      hv = ld2_uc(hp);
    } while (__float_as_uint(hv[0]) == SENT || __float_as_uint(hv[1]) == SENT);
    *(f32x2*)&h_lds[tid*2] = hv;
    __syncthreads();

    // 2 rows x 32 k per lane: weights from LDS (bf16), h from LDS (f32)
    float a0 = 0.f, a1 = 0.f;
    #pragma unroll
    for (int cp=0; cp<4; cp++){
      float4 ha = *(const float4*)&h_lds[(2*cp)*256 + l*4];
      float4 hb = *(const float4*)&h_lds[(2*cp+1)*256 + l*4];
      uint4 w0 = *(const uint4*)(smem + (size_t)((cp  )*1024 + tid)*16);
      uint4 w1 = *(const uint4*)(smem + (size_t)((4+cp)*1024 + tid)*16);
      a0 += blo(w0.x)*ha.x + bhi(w0.x)*ha.y + blo(w0.y)*ha.z + bhi(w0.y)*ha.w
          + blo(w0.z)*hb.x + bhi(w0.z)*hb.y + blo(w0.w)*hb.z + bhi(w0.w)*hb.w;
      a1 += blo(w1.x)*ha.x + bhi(w1.x)*ha.y + blo(w1.y)*ha.z + bhi(w1.y)*ha.w
          + blo(w1.z)*hb.x + bhi(w1.z)*hb.y + blo(w1.w)*hb.z + bhi(w1.w)*hb.w;
    }
    #pragma unroll
    for (int off=32; off; off>>=1){
      a0 += __shfl_xor(a0, off, 64);
      a1 += __shfl_xor(a1, off, 64);
    }
    if (l == 0){ gsum[2*w] = a0; gsum[2*w+1] = a1; }
    __syncthreads();

    // cell update + publish (lanes 0..7)
    if (tid < 8){
      float ipre = gsum[tid]    + xpv[0];
      float fpre = gsum[8+tid]  + xpv[1];
      float gpre = gsum[16+tid] + xpv[2];
      float opre = gsum[24+tid] + xpv[3];
      float iv = 1.f/(1.f + __expf(-ipre));
      float fv = 1.f/(1.f + __expf(-fpre));
      float e2 = __expf(-2.f*gpre);
      float gv = (1.f - e2)/(1.f + e2);
      float ov = 1.f/(1.f + __expf(-opre));
      c_reg = fv*c_reg + iv*gv;
      float e2c = __expf(-2.f*c_reg);
      float th = (1.f - e2c)/(1.f + e2c);
      st_uc(Hbuf + (size_t)(t+1)*HD + g*8 + tid, ov*th);
    }
  }
}

// ---------------- phase 3: y[t] = h_t . W_out + b_out ----------------
__global__ __launch_bounds__(256) void out_gemv(const float* __restrict__ Hbuf,
                                                const float* __restrict__ Wout,
                                                const float* __restrict__ bout,
                                                float* __restrict__ y){
  const int t = blockIdx.x;
  const int tid = threadIdx.x;
  const float* h = Hbuf + (size_t)(t+1)*HD;
  float4 a0 = *(const float4*)(h + tid*8);
  float4 a1 = *(const float4*)(h + tid*8 + 4);
  float4 w0 = *(const float4*)(Wout + tid*8);
  float4 w1 = *(const float4*)(Wout + tid*8 + 4);
  float s = a0.x*w0.x + a0.y*w0.y + a0.z*w0.z + a0.w*w0.w
          + a1.x*w1.x + a1.y*w1.y + a1.z*w1.z + a1.w*w1.w;
  #pragma unroll
  for (int off=32; off; off>>=1) s += __shfl_xor(s, off, 64);
  __shared__ float ps[4];
  if ((tid & 63) == 0) ps[tid>>6] = s;
  __syncthreads();
  if (tid == 0) y[t] = ps[0]+ps[1]+ps[2]+ps[3] + bout[0];
}

extern "C" void kernel_launch(void* const* d_in, const int* in_sizes, int n_in,
                              void* d_out, int out_size, void* d_ws, size_t ws_size,
                              hipStream_t stream) {
  const float* x    = (const float*)d_in[0];
  const float* Wih  = (const float*)d_in[1];
  const float* Whh  = (const float*)d_in[2];
  const float* b_ih = (const float*)d_in[3];
  const float* b_hh = (const float*)d_in[4];
  const float* Wout = (const float*)d_in[5];
  const float* bout = (const float*)d_in[6];
  float* y = (float*)d_out;

  char* ws = (char*)d_ws;
  unsigned short* XP = (unsigned short*)(ws);                 // 4096*8192*2  = 67108864
  float* Hbuf        = (float*)(ws + 67108864);               // 4097*2048*4  = 33562624
  float* bias        = (float*)(ws + 100671488);              // 8192*4       = 32768

  init_kernel<<<2048, 256, 0, stream>>>(b_ih, b_hh, bias, Hbuf);
  gemm_xp<<<2048, 256, 0, stream>>>(x, Wih, bias, XP);

  hipFuncSetAttribute((const void*)recur,
                      hipFuncAttributeMaxDynamicSharedMemorySize, SMEM_BYTES);
  void* args[] = {(void*)&XP, (void*)&Whh, (void*)&Hbuf};
  hipLaunchCooperativeKernel((void*)recur, dim3(NWG), dim3(NTH), args,
                             SMEM_BYTES, stream);

  out_gemv<<<T_STEPS, 256, 0, stream>>>(Hbuf, Wout, bout, y);
}

// Round 4
// 10745.714 us; speedup vs baseline: 1.1071x; 1.1071x over previous
//
#include <hip/hip_runtime.h>

#define T_STEPS 4096
#define HD 2048
#define G4 8192
#define NWG 256
#define NTH 1024
#define HSENT 0xFF80u
#define HSENT2 0xFF80FF80u

#define HB_OFF  131072                  // weights: 128 KB; then 2x4 KB h double-buffer
#define P_OFF   (131072 + 8192)         // partials: 16 waves x 32 f32 = 2 KB
#define SMEM_BYTES (131072 + 8192 + 2048)

typedef __attribute__((ext_vector_type(8))) short bf16x8;
typedef __attribute__((ext_vector_type(4))) float f32x4;
typedef __attribute__((ext_vector_type(8))) unsigned short u16x8;

static __device__ __forceinline__ unsigned short f2bf(float f){
  union { float f; unsigned int u; } v; v.f = f;
  unsigned int r = (v.u + 0x7fffu + ((v.u >> 16) & 1u)) >> 16;
  return (unsigned short)r;
}
static __device__ __forceinline__ float bf2f(unsigned short s){
  union { unsigned int u; float f; } v; v.u = ((unsigned int)s) << 16;
  return v.f;
}

// uncached (coherence-point) 4B load — bypasses L1/L2, no fences needed
static __device__ __forceinline__ unsigned int ld1_uc(const unsigned int* p){
  unsigned int r;
  asm volatile("global_load_dword %0, %1, off sc0 sc1\n\ts_waitcnt vmcnt(0)"
               : "=v"(r) : "v"(p) : "memory");
  return r;
}
// write-through 2B store
static __device__ __forceinline__ void st2_uc(unsigned short* p, unsigned int v){
  asm volatile("global_store_short %0, %1, off sc0 sc1" :: "v"(p), "v"(v) : "memory");
}

// ---------------- init: bias fuse + h0 zeros + sentinel rows (bf16) ----------------
__global__ void init_kernel(const float* __restrict__ b_ih, const float* __restrict__ b_hh,
                            float* __restrict__ bias, unsigned int* __restrict__ Hb32){
  int i = blockIdx.x*blockDim.x + threadIdx.x;
  int stride = gridDim.x*blockDim.x;
  const int HB_U32 = (T_STEPS+1)*HD/2;      // 4097*1024
  const int NTOT = G4 + HB_U32;
  for (int idx = i; idx < NTOT; idx += stride){
    if (idx < G4) bias[idx] = b_ih[idx] + b_hh[idx];
    else {
      int j = idx - G4;
      Hb32[j] = (j < HD/2) ? 0u : HSENT2;   // row 0 = bf16 zeros, rest sentinel
    }
  }
}

// ---------------- phase 1: XP = x @ W_ih^T + (b_ih+b_hh), bf16 out ----------------
__global__ __launch_bounds__(256) void gemm_xp(const float* __restrict__ X,
                                               const float* __restrict__ W,
                                               const float* __restrict__ bias,
                                               unsigned short* __restrict__ XP){
  __shared__ __align__(16) unsigned short As[128][40];
  __shared__ __align__(16) unsigned short Bs[128][40];
  const int tid = threadIdx.x;
  const int bx = blockIdx.x & 63;
  const int by = blockIdx.x >> 6;
  const int row0 = by*128, col0 = bx*128;
  const int l = tid & 63, w = tid >> 6;
  const int wrow = (w>>1)*64, wcol = (w&1)*64;
  const int lr = l & 15, lk = l >> 4;

  f32x4 acc[4][4];
  #pragma unroll
  for (int mi=0; mi<4; mi++)
    #pragma unroll
    for (int ni=0; ni<4; ni++)
      acc[mi][ni] = (f32x4){0.f,0.f,0.f,0.f};

  const int sr = tid >> 1;
  const int sh = (tid & 1) * 16;
  const float* xb = X + (size_t)(row0+sr)*2048 + sh;
  const float* wb = W + (size_t)(col0+sr)*2048 + sh;

  for (int k0 = 0; k0 < 2048; k0 += 32){
    __syncthreads();
    u16x8 va[2], vb[2];
    #pragma unroll
    for (int q=0; q<2; q++){
      float4 u = *(const float4*)(xb + k0 + q*8);
      float4 v = *(const float4*)(xb + k0 + q*8 + 4);
      u16x8 t;
      t[0]=f2bf(u.x); t[1]=f2bf(u.y); t[2]=f2bf(u.z); t[3]=f2bf(u.w);
      t[4]=f2bf(v.x); t[5]=f2bf(v.y); t[6]=f2bf(v.z); t[7]=f2bf(v.w);
      va[q]=t;
      float4 p = *(const float4*)(wb + k0 + q*8);
      float4 r = *(const float4*)(wb + k0 + q*8 + 4);
      u16x8 s;
      s[0]=f2bf(p.x); s[1]=f2bf(p.y); s[2]=f2bf(p.z); s[3]=f2bf(p.w);
      s[4]=f2bf(r.x); s[5]=f2bf(r.y); s[6]=f2bf(r.z); s[7]=f2bf(r.w);
      vb[q]=s;
    }
    *(u16x8*)&As[sr][sh]   = va[0];
    *(u16x8*)&As[sr][sh+8] = va[1];
    *(u16x8*)&Bs[sr][sh]   = vb[0];
    *(u16x8*)&Bs[sr][sh+8] = vb[1];
    __syncthreads();

    bf16x8 af[4], bfr[4];
    #pragma unroll
    for (int mi=0; mi<4; mi++) af[mi]  = *(const bf16x8*)&As[wrow+mi*16+lr][lk*8];
    #pragma unroll
    for (int ni=0; ni<4; ni++) bfr[ni] = *(const bf16x8*)&Bs[wcol+ni*16+lr][lk*8];
    #pragma unroll
    for (int mi=0; mi<4; mi++)
      #pragma unroll
      for (int ni=0; ni<4; ni++)
        acc[mi][ni] = __builtin_amdgcn_mfma_f32_16x16x32_bf16(af[mi], bfr[ni], acc[mi][ni], 0,0,0);
  }

  #pragma unroll
  for (int ni=0; ni<4; ni++){
    const int jc = col0 + wcol + ni*16 + lr;
    const float bv = bias[jc];
    #pragma unroll
    for (int mi=0; mi<4; mi++){
      const int tr0 = row0 + wrow + mi*16 + lk*4;
      #pragma unroll
      for (int r=0; r<4; r++)
        XP[(size_t)(tr0+r)*G4 + jc] = f2bf(acc[mi][ni][r] + bv);
    }
  }
}

// ---------------- phase 2: persistent LSTM recurrence (MFMA) ----------------
// 256 WGs x 1024 thr (16 waves). WG g owns h-dims [8g,8g+8) = 32 gate rows
// rr = gate*8+dd (global W row = (rr>>3)*2048 + g*8 + (rr&7)).
// Per step: gates(1x32) = h(1x2048) @ W^T via mfma_f32_16x16x32_bf16:
//   wave w covers K-slice [w*128, w*128+128) x both 16-col tiles = 8 MFMAs.
//   A-frag: same-address LDS broadcast of h -> all 16 rows compute the same
//   (correct) GEMV; row 0 (lanes 0-15, reg 0) is used.
// Weights staged once in LDS pre-swizzled as B-fragments (128 KB).
// Sync: bf16 sentinel (0xFF80 = -inf, unreachable) poll on uncached loads,
// write-through bf16 publish, no fences/atomics. B-frag reads issued before
// the poll: lgkmcnt and vmcnt are independent -> weight reads hide under poll.
__global__ __launch_bounds__(NTH, 4) void recur(const unsigned short* __restrict__ XP,
                                                const float* __restrict__ Whh,
                                                unsigned short* __restrict__ Hbuf){
  extern __shared__ char smem[];
  float* part = (float*)(smem + P_OFF);
  const int g = blockIdx.x;
  const int tid = threadIdx.x;
  const int l = tid & 63, w = tid >> 6;

  // ---- stage weights as pre-swizzled MFMA B-fragments ----
  #pragma unroll
  for (int n=0; n<2; n++)
    #pragma unroll
    for (int kt=0; kt<4; kt++){
      const int rr = n*16 + (l & 15);
      const size_t jrow = (size_t)(rr>>3)*HD + (size_t)g*8 + (rr&7);
      const int k = w*128 + kt*32 + (l>>4)*8;
      const float* wp = Whh + jrow*HD + k;
      float4 fa = *(const float4*)wp;
      float4 fb = *(const float4*)(wp + 4);
      uint4 pk;
      pk.x = ((unsigned)f2bf(fa.y)<<16) | f2bf(fa.x);
      pk.y = ((unsigned)f2bf(fa.w)<<16) | f2bf(fa.z);
      pk.z = ((unsigned)f2bf(fb.y)<<16) | f2bf(fb.x);
      pk.w = ((unsigned)f2bf(fb.w)<<16) | f2bf(fb.z);
      *(uint4*)(smem + (size_t)(((w*8 + n*4 + kt)*64 + l)*16)) = pk;
    }
  __syncthreads();

  float c_reg = 0.f;   // cell state (lanes tid<8)

  for (int t=0; t<T_STEPS; ++t){
    // XP slice for cell lanes (cached loads, independent of h)
    float xpv0=0.f, xpv1=0.f, xpv2=0.f, xpv3=0.f;
    if (tid < 8){
      const unsigned short* xp = XP + (size_t)t*G4 + (size_t)g*8 + tid;
      xpv0 = bf2f(xp[0]);
      xpv1 = bf2f(xp[HD]);
      xpv2 = bf2f(xp[2*HD]);
      xpv3 = bf2f(xp[3*HD]);
    }
    // B-fragments (loop-invariant LDS reads) issued BEFORE the poll
    bf16x8 bfr0[4], bfr1[4];
    #pragma unroll
    for (int kt=0; kt<4; kt++){
      bfr0[kt] = *(const bf16x8*)(smem + (size_t)(((w*8 +      kt)*64 + l)*16));
      bfr1[kt] = *(const bf16x8*)(smem + (size_t)(((w*8 + 4 + kt)*64 + l)*16));
    }

    // spin-wait on own 4B (2 bf16) of h[t-1] (row t; row 0 = zeros)
    unsigned int hv;
    {
      const unsigned int* hp = (const unsigned int*)(Hbuf + (size_t)t*HD) + tid;
      do { hv = ld1_uc(hp); }
      while ((hv & 0xFFFFu) == HSENT || (hv >> 16) == HSENT);
    }
    unsigned int* hdst = (unsigned int*)(smem + HB_OFF + (t&1)*4096);
    hdst[tid] = hv;
    __syncthreads();

    // A-fragments: broadcast h (same addr within each 16-lane group)
    const char* hb = smem + HB_OFF + (t&1)*4096;
    bf16x8 af[4];
    #pragma unroll
    for (int kt=0; kt<4; kt++)
      af[kt] = *(const bf16x8*)(hb + (w*256 + kt*64 + (l>>4)*16));

    f32x4 acc0 = (f32x4){0.f,0.f,0.f,0.f};
    f32x4 acc1 = (f32x4){0.f,0.f,0.f,0.f};
    #pragma unroll
    for (int kt=0; kt<4; kt++){
      acc0 = __builtin_amdgcn_mfma_f32_16x16x32_bf16(af[kt], bfr0[kt], acc0, 0,0,0);
      acc1 = __builtin_amdgcn_mfma_f32_16x16x32_bf16(af[kt], bfr1[kt], acc1, 0,0,0);
    }
    // row 0 of D = lanes 0..15, reg 0
    if (l < 16){
      part[w*32 + l]      = acc0[0];
      part[w*32 + 16 + l] = acc1[0];
    }
    __syncthreads();

    // wave 0: reduce 16 partials per gate-row, cell update, publish
    if (w == 0 && l < 32){
      float tot = 0.f;
      #pragma unroll
      for (int q=0; q<16; q++) tot += part[q*32 + l];
      float fg = __shfl_down(tot, 8, 64);
      float gg = __shfl_down(tot, 16, 64);
      float og = __shfl_down(tot, 24, 64);
      if (l < 8){
        float ipre = tot + xpv0;
        float fpre = fg  + xpv1;
        float gpre = gg  + xpv2;
        float opre = og  + xpv3;
        float iv = 1.f/(1.f + __expf(-ipre));
        float fv = 1.f/(1.f + __expf(-fpre));
        float e2 = __expf(-2.f*gpre);
        float gv = (1.f - e2)/(1.f + e2);
        float ov = 1.f/(1.f + __expf(-opre));
        c_reg = fv*c_reg + iv*gv;
        float e2c = __expf(-2.f*c_reg);
        float th = (1.f - e2c)/(1.f + e2c);
        st2_uc(Hbuf + (size_t)(t+1)*HD + (size_t)g*8 + l, (unsigned int)f2bf(ov*th));
      }
    }
  }
}

// ---------------- phase 3: y[t] = h_t . W_out + b_out (h is bf16) ----------------
__global__ __launch_bounds__(256) void out_gemv(const unsigned short* __restrict__ Hbuf,
                                                const float* __restrict__ Wout,
                                                const float* __restrict__ bout,
                                                float* __restrict__ y){
  const int t = blockIdx.x;
  const int tid = threadIdx.x;
  u16x8 hv = *(const u16x8*)(Hbuf + (size_t)(t+1)*HD + tid*8);
  float4 w0 = *(const float4*)(Wout + tid*8);
  float4 w1 = *(const float4*)(Wout + tid*8 + 4);
  float s = bf2f(hv[0])*w0.x + bf2f(hv[1])*w0.y + bf2f(hv[2])*w0.z + bf2f(hv[3])*w0.w
          + bf2f(hv[4])*w1.x + bf2f(hv[5])*w1.y + bf2f(hv[6])*w1.z + bf2f(hv[7])*w1.w;
  #pragma unroll
  for (int off=32; off; off>>=1) s += __shfl_xor(s, off, 64);
  __shared__ float ps[4];
  if ((tid & 63) == 0) ps[tid>>6] = s;
  __syncthreads();
  if (tid == 0) y[t] = ps[0]+ps[1]+ps[2]+ps[3] + bout[0];
}

extern "C" void kernel_launch(void* const* d_in, const int* in_sizes, int n_in,
                              void* d_out, int out_size, void* d_ws, size_t ws_size,
                              hipStream_t stream) {
  const float* x    = (const float*)d_in[0];
  const float* Wih  = (const float*)d_in[1];
  const float* Whh  = (const float*)d_in[2];
  const float* b_ih = (const float*)d_in[3];
  const float* b_hh = (const float*)d_in[4];
  const float* Wout = (const float*)d_in[5];
  const float* bout = (const float*)d_in[6];
  float* y = (float*)d_out;

  char* ws = (char*)d_ws;
  unsigned short* XP   = (unsigned short*)(ws);               // 4096*8192*2   = 67108864
  unsigned short* Hbuf = (unsigned short*)(ws + 67108864);    // 4097*2048*2   = 16781312
  float* bias          = (float*)(ws + 83890176);             // 8192*4        = 32768

  init_kernel<<<2048, 256, 0, stream>>>(b_ih, b_hh, bias, (unsigned int*)Hbuf);
  gemm_xp<<<2048, 256, 0, stream>>>(x, Wih, bias, XP);

  hipFuncSetAttribute((const void*)recur,
                      hipFuncAttributeMaxDynamicSharedMemorySize, SMEM_BYTES);
  void* args[] = {(void*)&XP, (void*)&Whh, (void*)&Hbuf};
  hipLaunchCooperativeKernel((void*)recur, dim3(NWG), dim3(NTH), args,
                             SMEM_BYTES, stream);

  out_gemv<<<T_STEPS, 256, 0, stream>>>(Hbuf, Wout, bout, y);
}